// Round 3
// baseline (419.791 us; speedup 1.0000x reference)
//
#include <hip/hip_runtime.h>

// 2-layer LSTM (B=4096, T=256, I=38, H1=50, H2=15) + FC on last step.
// r'=4u+g row packing (17 tiles of 16 gate-rows), 8 waves/block (2/SIMD),
// DPP quad_perm cross-lane LSTM update: each lane does ONE activation.
// One barrier per step; L2 pipelined one step behind L1.

typedef _Float16 f16x8 __attribute__((ext_vector_type(8)));
typedef float    f32x4 __attribute__((ext_vector_type(4)));

#if __has_builtin(__builtin_amdgcn_exp2f)
#define DEV_EXP2(x) __builtin_amdgcn_exp2f(x)
#else
#define DEV_EXP2(x) exp2f(x)
#endif
#if __has_builtin(__builtin_amdgcn_rcpf)
#define DEV_RCP(x) __builtin_amdgcn_rcpf(x)
#else
#define DEV_RCP(x) (1.0f/(x))
#endif

#if __has_builtin(__builtin_amdgcn_mov_dpp)
template<int CTRL>
__device__ __forceinline__ float dppq(float v) {
  return __int_as_float(__builtin_amdgcn_mov_dpp(__float_as_int(v), CTRL, 0xF, 0xF, true));
}
#define DPP_XOR1(v) dppq<0xB1>(v)   // quad_perm [1,0,3,2]
#define DPP_XOR2(v) dppq<0x4E>(v)   // quad_perm [2,3,0,1]
#else
#define DPP_XOR1(v) __shfl_xor((v), 1, 64)
#define DPP_XOR2(v) __shfl_xor((v), 2, 64)
#endif

#define I1 38
#define H1 50
#define H2 15
#define NC 14
#define TT 256
#define SB 16
// A-row (f16): [x:0..37 | h1:38..87 | h2:88..102 | zero:103..127 | pad..135]
#define XS 136
#define NTH 512
#define NSLOT 3
#define L2E 2.885390081777927f   // 2*log2(e)
#define L1E 1.442695040888963f

__launch_bounds__(NTH, 2)
__global__ void lstm2_fused(const float* __restrict__ x,
                            const float* __restrict__ w_ih1, const float* __restrict__ w_hh1,
                            const float* __restrict__ b_ih1, const float* __restrict__ b_hh1,
                            const float* __restrict__ w_ih2, const float* __restrict__ w_hh2,
                            const float* __restrict__ b_ih2, const float* __restrict__ b_hh2,
                            const float* __restrict__ w_fc, const float* __restrict__ b_fc,
                            float* __restrict__ out)
{
  __shared__ __align__(16) _Float16 bufA[2][SB][XS];

  const int tid  = threadIdx.x;
  const int wv   = tid >> 6;
  const int lane = tid & 63;
  const int lm   = lane & 15;   // tile column (gate-row) for B/C; seq row for A reads
  const int lk   = lane >> 4;
  const int q    = lm & 3;      // gate role: 0=i 1=f 2=g~ 3=o
  const int blk  = blockIdx.x;
  const float* xblk = x + (size_t)blk * SB * TT * I1;

  // ---- zero both A buffers ----
  for (int i = tid; i < 2*SB*XS; i += NTH) ((_Float16*)bufA)[i] = (_Float16)0.f;

  // ---- activation role constants: act(v) = A + B*rcp(1 + exp2(C*v)) ----
  const float Acon = (q == 2) ? 1.f : 0.f;
  const float Bcon = (q == 2) ? -2.f : 1.f;
  const float Ccon = (q == 2) ? L2E : -L1E;

  // ---- slots: wave wv owns tiles {wv, wv+8} and (wv==7) tile 16 ----
  int   tile_[NSLOT]; bool sval_[NSLOT];
  #pragma unroll
  for (int s = 0; s < NSLOT; ++s) {
    int t = (s < 2) ? (wv + 8*s) : 16;
    bool v = (s < 2) || (wv == 7);
    tile_[s] = t; sval_[s] = v;
  }

  // per-slot per-lane geometry
  bool isl1_[NSLOT], colv_[NSLOT];
  int  dest_[NSLOT], kmask_[NSLOT];
  float sb_[NSLOT];
  f16x8 W[NSLOT][4];
  #pragma unroll
  for (int s = 0; s < NSLOT; ++s) {
    const int t = tile_[s];
    const int r = t*16 + lm;          // gate-row id
    const int qi = r >> 2;            // unit-quad id, 0..64 valid
    const bool il1 = (qi < 50);
    const int  u   = il1 ? qi : (qi - 50);
    isl1_[s] = il1;
    colv_[s] = sval_[s] && (r < 260);
    dest_[s] = il1 ? (38 + u) : (88 + u);
    kmask_[s] = (t < 12) ? 0x7 : (t == 12 ? 0xF : 0xE);
    // bias
    float b = 0.f;
    if (colv_[s]) {
      int g = r & 3;
      b = il1 ? (b_ih1[g*H1 + u] + b_hh1[g*H1 + u])
              : (b_ih2[g*H2 + u] + b_hh2[g*H2 + u]);
    }
    sb_[s] = b;
    // weights
    #pragma unroll
    for (int ks = 0; ks < 4; ++ks) {
      f16x8 v;
      #pragma unroll
      for (int e = 0; e < 8; ++e) {
        const int k = ks*32 + lk*8 + e;
        float w = 0.f;
        if (colv_[s]) {
          int g = r & 3;
          if (il1) {
            if (k < I1)              w = w_ih1[(g*H1 + u)*I1 + k];
            else if (k < I1 + H1)    w = w_hh1[(g*H1 + u)*H1 + (k - I1)];
          } else {
            if (k >= I1 && k < I1 + H1)            w = w_ih2[(g*H2 + u)*H1 + (k - I1)];
            else if (k >= I1 + H1 && k < I1+H1+H2) w = w_hh2[(g*H2 + u)*H2 + (k - I1 - H1)];
          }
        }
        v[e] = (_Float16)w;
      }
      W[s][ks] = v;
    }
  }

  // ---- x staging map: 608 f32/step over 512 threads ----
  const int e0 = tid, e1 = 512 + tid;
  const bool v1 = (tid < SB*I1 - 512);
  const int s0 = e0 / I1, k0 = e0 % I1;
  const int s1 = e1 / I1, k1 = e1 % I1;
  const int gb0 = s0*TT*I1 + k0, gb1 = v1 ? (s1*TT*I1 + k1) : 0;
  const int lb0 = s0*XS + k0,    lb1 = v1 ? (s1*XS + k1) : 0;

  __syncthreads();            // zeros visible
  {                           // stage x(0) into buf[0]
    _Float16* b0 = &bufA[0][0][0];
    b0[lb0] = (_Float16)xblk[gb0];
    if (v1) b0[lb1] = (_Float16)xblk[gb1];
  }
  __syncthreads();

  float cst[NSLOT][4] = {};   // cell state, meaningful on q==1 lanes

  for (int t = 0; t <= TT; ++t) {
    _Float16* cur = &bufA[t & 1][0][0];
    _Float16* nxt = &bufA[(t & 1) ^ 1][0][0];

    // T14: issue x(t+1) loads early, consume at step end
    const bool px = (t + 1 < TT);
    float xr0 = 0.f, xr1 = 0.f;
    if (px) {
      const int go = (t + 1) * I1;
      xr0 = xblk[gb0 + go];
      if (v1) xr1 = xblk[gb1 + go];
    }

    // A fragments
    f16x8 a[4];
    #pragma unroll
    for (int ks = 0; ks < 4; ++ks)
      a[ks] = *(const f16x8*)(cur + lm*XS + ks*32 + lk*8);

    #pragma unroll
    for (int s = 0; s < NSLOT; ++s) {
      if (!sval_[s]) continue;                       // wave-uniform
      f32x4 acc = (f32x4){sb_[s], sb_[s], sb_[s], sb_[s]};
      const int km = kmask_[s];
      #pragma unroll
      for (int ks = 0; ks < 4; ++ks)
        if (km & (1 << ks))
          acc = __builtin_amdgcn_mfma_f32_16x16x32_f16(a[ks], W[s][ks], acc, 0, 0, 0);

      const bool upd = isl1_[s] ? (t < TT) : (t >= 1);
      #pragma unroll
      for (int m = 0; m < 4; ++m) {
        const float v  = acc[m];
        const float aact = Acon + Bcon * DEV_RCP(1.f + DEV_EXP2(Ccon * v));
        const float b2 = DPP_XOR2(aact);   // i<->g~, f<->o
        const float p  = aact * b2;        // lane q0: i*g~
        const float pp = DPP_XOR1(p);      // q1 receives i*g~
        const float cn = aact * cst[s][m] + pp;   // q1: f*c + i*g~
        const float cx = DPP_XOR2(cn);     // q3 receives c'
        const float Tn = 1.f - 2.f * DEV_RCP(1.f + DEV_EXP2(L2E * cx));
        const float h  = aact * Tn;        // q3: o * tanh(c')
        if (upd && q == 1) cst[s][m] = cn;
        if (upd && q == 3 && colv_[s])
          nxt[(4*lk + m)*XS + dest_[s]] = (_Float16)h;
      }
    }

    // stage x(t+1) into next buffer
    if (px) {
      nxt[lb0] = (_Float16)xr0;
      if (v1) nxt[lb1] = (_Float16)xr1;
    }

    __syncthreads();
  }

  // ---- FC on h2(255) (bufA[1], cols 88..102) ----
  if (tid < SB*NC) {
    int s = tid / NC, n = tid % NC;
    float acc = b_fc[n];
    #pragma unroll
    for (int u = 0; u < H2; ++u)
      acc += (float)bufA[1][s][88 + u] * w_fc[n*H2 + u];
    out[((size_t)blk*SB + s)*NC + n] = acc;
  }
}

extern "C" void kernel_launch(void* const* d_in, const int* in_sizes, int n_in,
                              void* d_out, int out_size, void* d_ws, size_t ws_size,
                              hipStream_t stream) {
  (void)n_in; (void)d_ws; (void)ws_size; (void)out_size;
  const float* x     = (const float*)d_in[0];
  const float* w_ih1 = (const float*)d_in[1];
  const float* w_hh1 = (const float*)d_in[2];
  const float* b_ih1 = (const float*)d_in[3];
  const float* b_hh1 = (const float*)d_in[4];
  const float* w_ih2 = (const float*)d_in[5];
  const float* w_hh2 = (const float*)d_in[6];
  const float* b_ih2 = (const float*)d_in[7];
  const float* b_hh2 = (const float*)d_in[8];
  const float* w_fc  = (const float*)d_in[9];
  const float* b_fc  = (const float*)d_in[10];
  float* out = (float*)d_out;

  const int B = in_sizes[0] / (TT * I1);   // 4096
  dim3 grid(B / SB), block(NTH);
  lstm2_fused<<<grid, block, 0, stream>>>(x, w_ih1, w_hh1, b_ih1, b_hh1,
                                          w_ih2, w_hh2, b_ih2, b_hh2,
                                          w_fc, b_fc, out);
}

// Round 4
// 322.438 us; speedup vs baseline: 1.3019x; 1.3019x over previous
//
#include <hip/hip_runtime.h>

// 2-layer LSTM (B=4096, T=256, I=38, H1=50, H2=15) + FC on last step.
// R4: SB=8 seqs/block, 256 thr (4 waves), grid=512 -> 2 independent blocks/CU.
// Unified A = [x_t|h1(t-1)|h2(t-2)] (K=128), r'=4u+g gate rows, 17 column tiles.
// GEMM phase -> conflict-free LDS pre-act round-trip -> dense per-unit update.
// L2 pipelined one step behind L1. Two barriers per step.

typedef _Float16 f16x8 __attribute__((ext_vector_type(8)));
typedef float    f32x4 __attribute__((ext_vector_type(4)));

#if __has_builtin(__builtin_amdgcn_exp2f)
#define DEV_EXP2(x) __builtin_amdgcn_exp2f(x)
#else
#define DEV_EXP2(x) exp2f(x)
#endif
#if __has_builtin(__builtin_amdgcn_rcpf)
#define DEV_RCP(x) __builtin_amdgcn_rcpf(x)
#else
#define DEV_RCP(x) (1.0f/(x))
#endif

#define I1 38
#define H1 50
#define H2 15
#define NC 14
#define TT 256
#define SB 8
// A-row (f16): [x:0..37 | h1:38..87 | h2:88..102 | zero:..127 | pad..135]
#define XS 136
// pre-act row stride in f32: 276 -> (276*s + 4*q) banks fully spread, 16B aligned
#define PS 276
#define NTH 256
#define NSLOT 5
#define NQ 65            // valid unit-quads: 50 L1 + 15 L2
#define L2E 2.885390081777927f
#define L1E 1.442695040888963f

__device__ __forceinline__ float sigm(float v) {
  return DEV_RCP(1.f + DEV_EXP2(-L1E * v));
}
__device__ __forceinline__ float tanh_f(float v) {
  return 1.f - 2.f * DEV_RCP(1.f + DEV_EXP2(L2E * v));
}

__launch_bounds__(NTH, 2)
__global__ void lstm2_fused(const float* __restrict__ x,
                            const float* __restrict__ w_ih1, const float* __restrict__ w_hh1,
                            const float* __restrict__ b_ih1, const float* __restrict__ b_hh1,
                            const float* __restrict__ w_ih2, const float* __restrict__ w_hh2,
                            const float* __restrict__ b_ih2, const float* __restrict__ b_hh2,
                            const float* __restrict__ w_fc, const float* __restrict__ b_fc,
                            float* __restrict__ out)
{
  __shared__ __align__(16) _Float16 bufA[2][SB][XS];
  __shared__ __align__(16) float    s_pre[SB][PS];

  const int tid  = threadIdx.x;
  const int wv   = tid >> 6;
  const int lane = tid & 63;
  const int lm   = lane & 15;
  const int lk   = lane >> 4;
  const int arow = lm & 7;            // A-read row (seq), duplicated for lm>=8
  const int blk  = blockIdx.x;
  const float* xblk = x + (size_t)blk * SB * TT * I1;

  // ---- zero A buffers ----
  for (int i = tid; i < 2*SB*XS; i += NTH) ((_Float16*)bufA)[i] = (_Float16)0.f;

  // ---- slots: wave wv owns tiles {wv, wv+4, wv+8, wv+12}; wv3 also tile 16 ----
  bool sval_[NSLOT], colv_[NSLOT];
  int  tile_[NSLOT], kmask_[NSLOT];
  float sb_[NSLOT];
  f16x8 W[NSLOT][4];
  #pragma unroll
  for (int s = 0; s < NSLOT; ++s) {
    const int  t = (s < 4) ? (wv + 4*s) : 16;
    const bool v = (s < 4) || (wv == 3);
    tile_[s] = t; sval_[s] = v;
    kmask_[s] = (t < 12) ? 0x7 : (t == 12 ? 0xF : 0xE);
    const int r  = t*16 + lm;         // gate-row r' = 4u+g
    const int qi = r >> 2;
    const bool il1 = (qi < H1);
    const int  u   = il1 ? qi : (qi - H1);
    const int  g   = r & 3;
    colv_[s] = v && (qi < NQ);
    float b = 0.f;
    if (colv_[s])
      b = il1 ? (b_ih1[g*H1 + u] + b_hh1[g*H1 + u])
              : (b_ih2[g*H2 + u] + b_hh2[g*H2 + u]);
    sb_[s] = b;
    #pragma unroll
    for (int ks = 0; ks < 4; ++ks) {
      f16x8 vv;
      #pragma unroll
      for (int e = 0; e < 8; ++e) {
        const int k = ks*32 + lk*8 + e;
        float w = 0.f;
        if (colv_[s]) {
          if (il1) {
            if (k < I1)                w = w_ih1[(g*H1 + u)*I1 + k];
            else if (k < I1 + H1)      w = w_hh1[(g*H1 + u)*H1 + (k - I1)];
          } else {
            if (k >= I1 && k < I1+H1)             w = w_ih2[(g*H2 + u)*H1 + (k - I1)];
            else if (k >= I1+H1 && k < I1+H1+H2)  w = w_hh2[(g*H2 + u)*H2 + (k - I1 - H1)];
          }
        }
        vv[e] = (_Float16)w;
      }
      W[s][ks] = vv;
    }
  }

  // ---- x staging map: 304 f32/step over 256 threads ----
  const int e0 = tid, e1 = tid + 256;
  const bool v1 = (tid < SB*I1 - 256);   // tid < 48
  const int s0 = e0 / I1, k0 = e0 % I1;
  const int s1 = e1 / I1, k1 = e1 % I1;
  const int gb0 = s0*TT*I1 + k0, gb1 = v1 ? (s1*TT*I1 + k1) : 0;
  const int lb0 = s0*XS + k0,    lb1 = v1 ? (s1*XS + k1) : 0;

  // ---- update mapping: pair p = quad*8 + seq; p in {tid, tid+256, tid+512} ----
  // consecutive 8 lanes share a quad -> conflict-free f32x4 pre reads
  const int q0 = tid >> 3,          sq0 = tid & 7;
  const int q1 = (tid + 256) >> 3,  sq1 = tid & 7;
  const int q2 = (tid + 512) >> 3,  sq2 = tid & 7;
  const bool pv2 = (tid < SB*NQ - 512);     // tid < 8
  const bool il1u0 = (q0 < H1), il1u1 = (q1 < H1);
  const int  du0 = il1u0 ? (38 + q0) : (88 + q0 - H1);
  const int  du1 = il1u1 ? (38 + q1) : (88 + q1 - H1);
  const int  du2 = 88 + q2 - H1;            // q2 >= 64 -> always L2 when valid

  __syncthreads();              // zeros visible
  {                             // stage x(0)
    _Float16* b0 = &bufA[0][0][0];
    b0[lb0] = (_Float16)xblk[gb0];
    if (v1) b0[lb1] = (_Float16)xblk[gb1];
  }
  __syncthreads();

  float c0 = 0.f, c1 = 0.f, c2 = 0.f;     // cell states for the 3 pairs

  for (int t = 0; t <= TT; ++t) {
    _Float16* cur = &bufA[t & 1][0][0];
    _Float16* nxt = &bufA[(t & 1) ^ 1][0][0];

    // T14: issue x(t+1) loads early, consume at end of update phase
    const bool px = (t + 1 < TT);
    float xr0 = 0.f, xr1 = 0.f;
    if (px) {
      const int go = (t + 1) * I1;
      xr0 = xblk[gb0 + go];
      if (v1) xr1 = xblk[gb1 + go];
    }

    // ---- phase A: gate GEMM ----
    f16x8 a[4];
    #pragma unroll
    for (int ks = 0; ks < 4; ++ks)
      a[ks] = *(const f16x8*)(cur + arow*XS + ks*32 + lk*8);

    #pragma unroll
    for (int s = 0; s < NSLOT; ++s) {
      if (!sval_[s]) continue;                    // wave-uniform
      f32x4 acc = (f32x4){sb_[s], sb_[s], sb_[s], sb_[s]};
      const int km = kmask_[s];
      #pragma unroll
      for (int ks = 0; ks < 4; ++ks)
        if (km & (1 << ks))
          acc = __builtin_amdgcn_mfma_f32_16x16x32_f16(a[ks], W[s][ks], acc, 0, 0, 0);
      if (lk < 2) {
        const int col = tile_[s]*16 + lm;
        #pragma unroll
        for (int m = 0; m < 4; ++m)
          s_pre[4*lk + m][col] = acc[m];
      }
    }
    __syncthreads();   // bar1: pre-acts visible

    // ---- phase B: dense per-unit update ----
    {
      // pair 0
      {
        const bool upd = il1u0 ? (t < TT) : (t >= 1);
        if (upd) {
          f32x4 pre = *(const f32x4*)&s_pre[sq0][4*q0];
          float ig = sigm(pre[0]), fg = sigm(pre[1]);
          float gg = tanh_f(pre[2]), og = sigm(pre[3]);
          float cn = fg * c0 + ig * gg; c0 = cn;
          nxt[sq0*XS + du0] = (_Float16)(og * tanh_f(cn));
        }
      }
      // pair 1
      {
        const bool upd = il1u1 ? (t < TT) : (t >= 1);
        if (upd) {
          f32x4 pre = *(const f32x4*)&s_pre[sq1][4*q1];
          float ig = sigm(pre[0]), fg = sigm(pre[1]);
          float gg = tanh_f(pre[2]), og = sigm(pre[3]);
          float cn = fg * c1 + ig * gg; c1 = cn;
          nxt[sq1*XS + du1] = (_Float16)(og * tanh_f(cn));
        }
      }
      // pair 2 (8 threads)
      if (pv2 && t >= 1) {
        f32x4 pre = *(const f32x4*)&s_pre[sq2][4*q2];
        float ig = sigm(pre[0]), fg = sigm(pre[1]);
        float gg = tanh_f(pre[2]), og = sigm(pre[3]);
        float cn = fg * c2 + ig * gg; c2 = cn;
        nxt[sq2*XS + du2] = (_Float16)(og * tanh_f(cn));
      }
    }

    // stage x(t+1)
    if (px) {
      nxt[lb0] = (_Float16)xr0;
      if (v1) nxt[lb1] = (_Float16)xr1;
    }

    __syncthreads();   // bar2
  }

  // ---- FC on h2(255) (bufA[1], cols 88..102) ----
  if (tid < SB*NC) {
    int s = tid / NC, n = tid % NC;
    float acc = b_fc[n];
    #pragma unroll
    for (int u = 0; u < H2; ++u)
      acc += (float)bufA[1][s][88 + u] * w_fc[n*H2 + u];
    out[((size_t)blk*SB + s)*NC + n] = acc;
  }
}

extern "C" void kernel_launch(void* const* d_in, const int* in_sizes, int n_in,
                              void* d_out, int out_size, void* d_ws, size_t ws_size,
                              hipStream_t stream) {
  (void)n_in; (void)d_ws; (void)ws_size; (void)out_size;
  const float* x     = (const float*)d_in[0];
  const float* w_ih1 = (const float*)d_in[1];
  const float* w_hh1 = (const float*)d_in[2];
  const float* b_ih1 = (const float*)d_in[3];
  const float* b_hh1 = (const float*)d_in[4];
  const float* w_ih2 = (const float*)d_in[5];
  const float* w_hh2 = (const float*)d_in[6];
  const float* b_ih2 = (const float*)d_in[7];
  const float* b_hh2 = (const float*)d_in[8];
  const float* w_fc  = (const float*)d_in[9];
  const float* b_fc  = (const float*)d_in[10];
  float* out = (float*)d_out;

  const int B = in_sizes[0] / (TT * I1);   // 4096
  dim3 grid(B / SB), block(NTH);
  lstm2_fused<<<grid, block, 0, stream>>>(x, w_ih1, w_hh1, b_ih1, b_hh1,
                                          w_ih2, w_hh2, b_ih2, b_hh2,
                                          w_fc, b_fc, out);
}

// Round 5
// 266.546 us; speedup vs baseline: 1.5749x; 1.2097x over previous
//
#include <hip/hip_runtime.h>

// 2-layer LSTM (B=4096, T=256, I=38, H1=50, H2=15) + FC on last step.
// R5: SB=8, 4 waves, grid=512 (2 blocks/CU). ONE barrier per step:
// each wave writes AND reads back only its own tiles' pre-acts (wave-private
// LDS region, lgkmcnt-ordered); the barrier only publishes h (and x) for t+1.
// Two-step-ahead x prefetch (ping-pong regs) hides cold-HBM latency.
// L2 pipelined one step behind L1.

typedef _Float16 f16x8 __attribute__((ext_vector_type(8)));
typedef float    f32x4 __attribute__((ext_vector_type(4)));

#if __has_builtin(__builtin_amdgcn_exp2f)
#define DEV_EXP2(x) __builtin_amdgcn_exp2f(x)
#else
#define DEV_EXP2(x) exp2f(x)
#endif
#if __has_builtin(__builtin_amdgcn_rcpf)
#define DEV_RCP(x) __builtin_amdgcn_rcpf(x)
#else
#define DEV_RCP(x) (1.0f/(x))
#endif

#define I1 38
#define H1 50
#define H2 15
#define NC 14
#define TT 256
#define SB 8
// A-row (f16): [x:0..37 | h1:38..87 | h2:88..102 | zero:..127 | pad..135]
#define XS 136
#define NTH 256
#define NSLOT 5
#define NQ 65
#define PREW 640       // f32 per wave: 5 slots x 8 seqs x 16 cols
#define L2E 2.885390081777927f
#define L1E 1.442695040888963f

__device__ __forceinline__ float sigm(float v)  { return DEV_RCP(1.f + DEV_EXP2(-L1E * v)); }
__device__ __forceinline__ float tanh_f(float v){ return 1.f - 2.f * DEV_RCP(1.f + DEV_EXP2(L2E * v)); }

__launch_bounds__(NTH, 2)
__global__ void lstm2_fused(const float* __restrict__ x,
                            const float* __restrict__ w_ih1, const float* __restrict__ w_hh1,
                            const float* __restrict__ b_ih1, const float* __restrict__ b_hh1,
                            const float* __restrict__ w_ih2, const float* __restrict__ w_hh2,
                            const float* __restrict__ b_ih2, const float* __restrict__ b_hh2,
                            const float* __restrict__ w_fc, const float* __restrict__ b_fc,
                            float* __restrict__ out)
{
  __shared__ __align__(16) _Float16 bufA[2][SB][XS];
  __shared__ __align__(16) float    s_preb[4 * PREW];

  const int tid  = threadIdx.x;
  const int wv   = tid >> 6;
  const int lane = tid & 63;
  const int lm   = lane & 15;
  const int lk   = lane >> 4;
  const int arow = lm & 7;            // A-read row (seq), duplicated for lm>=8
  const int blk  = blockIdx.x;
  const float* xblk = x + (size_t)blk * SB * TT * I1;

  // ---- zero A buffers ----
  for (int i = tid; i < 2*SB*XS; i += NTH) ((_Float16*)bufA)[i] = (_Float16)0.f;

  // ---- slots: wave wv owns tiles {wv, wv+4, wv+8, wv+12}; wv3 also tile 16 ----
  bool sval_[NSLOT], colv_[NSLOT];
  int  kmask_[NSLOT];
  float sb_[NSLOT];
  f16x8 W[NSLOT][4];
  #pragma unroll
  for (int s = 0; s < NSLOT; ++s) {
    const int  t = (s < 4) ? (wv + 4*s) : 16;
    const bool v = (s < 4) || (wv == 3);
    sval_[s] = v;
    kmask_[s] = (t < 12) ? 0x7 : (t == 12 ? 0xF : 0xE);
    const int r  = t*16 + lm;          // gate-row r' = 4u+g
    const int qi = r >> 2;
    const bool il1 = (qi < H1);
    const int  u   = il1 ? qi : (qi - H1);
    const int  g   = r & 3;
    colv_[s] = v && (qi < NQ);
    float b = 0.f;
    if (colv_[s])
      b = il1 ? (b_ih1[g*H1 + u] + b_hh1[g*H1 + u])
              : (b_ih2[g*H2 + u] + b_hh2[g*H2 + u]);
    sb_[s] = b;
    #pragma unroll
    for (int ks = 0; ks < 4; ++ks) {
      f16x8 vv;
      #pragma unroll
      for (int e = 0; e < 8; ++e) {
        const int k = ks*32 + lk*8 + e;
        float w = 0.f;
        if (colv_[s]) {
          if (il1) {
            if (k < I1)                w = w_ih1[(g*H1 + u)*I1 + k];
            else if (k < I1 + H1)      w = w_hh1[(g*H1 + u)*H1 + (k - I1)];
          } else {
            if (k >= I1 && k < I1+H1)             w = w_ih2[(g*H2 + u)*H1 + (k - I1)];
            else if (k >= I1+H1 && k < I1+H1+H2)  w = w_hh2[(g*H2 + u)*H2 + (k - I1 - H1)];
          }
        }
        vv[e] = (_Float16)w;
      }
      W[s][ks] = vv;
    }
  }

  // ---- x staging map: 304 f32/step over 256 threads ----
  const int e1 = tid + 256;
  const bool v1 = (tid < SB*I1 - 256);   // tid < 48
  const int s0 = tid / I1, k0 = tid % I1;
  const int s1 = e1 / I1,  k1 = e1 % I1;
  const int gb0 = s0*TT*I1 + k0, gb1 = v1 ? (s1*TT*I1 + k1) : 0;
  const int lb0 = s0*XS + k0,    lb1 = v1 ? (s1*XS + k1) : 0;

  // ---- wave-local update pairs: slot s covers units 4*tile(s)..+3, seqs 0..7 ----
  // pair A: p = lane       -> slot lane>>5 (0,1)
  // pair B: p = lane + 64  -> slot 2 + (lane>>5)
  // pair C: wv3, lane<8    -> slot 4 (unit 64), seq = lane
  const int ulp = (lane >> 3) & 3, sqp = lane & 7;
  const int sA = lane >> 5, sB = 2 + (lane >> 5);
  const int uA = 4*(wv + 4*sA) + ulp;
  const int uB = 4*(wv + 4*sB) + ulp;
  const bool il1A = (uA < H1), il1B = (uB < H1);
  const int dA = il1A ? (38 + uA) : (88 + uA - H1);
  const int dB = il1B ? (38 + uB) : (88 + uB - H1);
  const int preA = wv*PREW + sA*128 + sqp*16 + 4*ulp;
  const int preB = wv*PREW + sB*128 + sqp*16 + 4*ulp;
  const bool hasC = (wv == 3) && (lane < 8);
  const int sqC = lane & 7;
  const int dC = 102;                  // unit 64 = L2 u14
  const int preC = 3*PREW + 4*128 + sqC*16;   // ulp=0

  __syncthreads();              // zeros visible
  {                             // stage x(0) directly
    _Float16* b0 = &bufA[0][0][0];
    b0[lb0] = (_Float16)xblk[gb0];
    if (v1) b0[lb1] = (_Float16)xblk[gb1];
  }
  float xA0 = 0.f, xA1 = 0.f, xB0 = 0.f, xB1 = 0.f;
  {                             // prefetch x(1) into regs A
    xA0 = xblk[gb0 + I1];
    if (v1) xA1 = xblk[gb1 + I1];
  }
  __syncthreads();

  float cA = 0.f, cB = 0.f, cC = 0.f;

#define STEP(T, XC0, XC1, XN0, XN1) do {                                        \
    _Float16* cur = &bufA[(T) & 1][0][0];                                       \
    _Float16* nxt = &bufA[((T) & 1) ^ 1][0][0];                                 \
    if ((T) + 2 < TT) {                /* issue x(T+2) loads */                 \
      const int go = ((T) + 2) * I1;                                            \
      XN0 = xblk[gb0 + go];                                                     \
      if (v1) XN1 = xblk[gb1 + go];                                             \
    }                                                                           \
    f16x8 a[4];                                                                 \
    _Pragma("unroll")                                                           \
    for (int ks = 0; ks < 4; ++ks)                                              \
      a[ks] = *(const f16x8*)(cur + arow*XS + ks*32 + lk*8);                    \
    _Pragma("unroll")                                                           \
    for (int s = 0; s < NSLOT; ++s) {                                           \
      if (!sval_[s]) continue;                                                  \
      f32x4 acc = (f32x4){sb_[s], sb_[s], sb_[s], sb_[s]};                      \
      const int km = kmask_[s];                                                 \
      _Pragma("unroll")                                                         \
      for (int ks = 0; ks < 4; ++ks)                                            \
        if (km & (1 << ks))                                                     \
          acc = __builtin_amdgcn_mfma_f32_16x16x32_f16(a[ks], W[s][ks], acc, 0, 0, 0); \
      if (lk < 2) {                                                             \
        _Pragma("unroll")                                                       \
        for (int m = 0; m < 4; ++m)                                             \
          s_preb[wv*PREW + s*128 + (4*lk + m)*16 + lm] = acc[m];                \
      }                                                                         \
    }                                                                           \
    { const bool up = il1A ? ((T) < TT) : ((T) >= 1);                           \
      if (up) { f32x4 p = *(const f32x4*)&s_preb[preA];                         \
        float ig = sigm(p[0]), fg = sigm(p[1]);                                 \
        float gg = tanh_f(p[2]), og = sigm(p[3]);                               \
        cA = fg*cA + ig*gg;                                                     \
        nxt[sqp*XS + dA] = (_Float16)(og * tanh_f(cA)); } }                     \
    { const bool up = il1B ? ((T) < TT) : ((T) >= 1);                           \
      if (up) { f32x4 p = *(const f32x4*)&s_preb[preB];                         \
        float ig = sigm(p[0]), fg = sigm(p[1]);                                 \
        float gg = tanh_f(p[2]), og = sigm(p[3]);                               \
        cB = fg*cB + ig*gg;                                                     \
        nxt[sqp*XS + dB] = (_Float16)(og * tanh_f(cB)); } }                     \
    if (hasC && (T) >= 1) {                                                     \
      f32x4 p = *(const f32x4*)&s_preb[preC];                                   \
      float ig = sigm(p[0]), fg = sigm(p[1]);                                   \
      float gg = tanh_f(p[2]), og = sigm(p[3]);                                 \
      cC = fg*cC + ig*gg;                                                       \
      nxt[sqC*XS + dC] = (_Float16)(og * tanh_f(cC)); }                         \
    if ((T) + 1 < TT) {                /* publish x(T+1), loaded 2 steps ago */ \
      nxt[lb0] = (_Float16)XC0;                                                 \
      if (v1) nxt[lb1] = (_Float16)XC1;                                         \
    }                                                                           \
    __syncthreads();                                                            \
  } while (0)

  int t = 0;
  for (;;) {
    STEP(t, xA0, xA1, xB0, xB1);
    if (++t > TT) break;
    STEP(t, xB0, xB1, xA0, xA1);
    if (++t > TT) break;
  }
#undef STEP

  // ---- FC on h2(255) (bufA[1], cols 88..102) ----
  if (tid < SB*NC) {
    int s = tid / NC, n = tid % NC;
    float acc = b_fc[n];
    #pragma unroll
    for (int u = 0; u < H2; ++u)
      acc += (float)bufA[1][s][88 + u] * w_fc[n*H2 + u];
    out[((size_t)blk*SB + s)*NC + n] = acc;
  }
}

extern "C" void kernel_launch(void* const* d_in, const int* in_sizes, int n_in,
                              void* d_out, int out_size, void* d_ws, size_t ws_size,
                              hipStream_t stream) {
  (void)n_in; (void)d_ws; (void)ws_size; (void)out_size;
  const float* x     = (const float*)d_in[0];
  const float* w_ih1 = (const float*)d_in[1];
  const float* w_hh1 = (const float*)d_in[2];
  const float* b_ih1 = (const float*)d_in[3];
  const float* b_hh1 = (const float*)d_in[4];
  const float* w_ih2 = (const float*)d_in[5];
  const float* w_hh2 = (const float*)d_in[6];
  const float* b_ih2 = (const float*)d_in[7];
  const float* b_hh2 = (const float*)d_in[8];
  const float* w_fc  = (const float*)d_in[9];
  const float* b_fc  = (const float*)d_in[10];
  float* out = (float*)d_out;

  const int B = in_sizes[0] / (TT * I1);   // 4096
  dim3 grid(B / SB), block(NTH);
  lstm2_fused<<<grid, block, 0, stream>>>(x, w_ih1, w_hh1, b_ih1, b_hh1,
                                          w_ih2, w_hh2, b_ih2, b_hh2,
                                          w_fc, b_fc, out);
}